// Round 15
// baseline (270.081 us; speedup 1.0000x reference)
//
#include <hip/hip_runtime.h>
#include <math.h>

#define B_SZ   1024
#define CDIM   768
#define POOL   100
#define COSEPS 1e-6f
#define NTHR   256
#define BATCH4 2048   // float4s per batch = 8 * NTHR (32 KB)

typedef __attribute__((ext_vector_type(4))) float f32x4;

#define LOAD8(v, base)                                                       \
    do { const f32x4* _s = (base);                                           \
         v##0 = _s[0];        v##1 = _s[NTHR];     v##2 = _s[2 * NTHR];      \
         v##3 = _s[3 * NTHR]; v##4 = _s[4 * NTHR]; v##5 = _s[5 * NTHR];      \
         v##6 = _s[6 * NTHR]; v##7 = _s[7 * NTHR]; } while (0)
#define STORE8(v, base)                                                      \
    do { f32x4* _d = (base);                                                 \
         _d[0] = v##0;        _d[NTHR] = v##1;     _d[2 * NTHR] = v##2;      \
         _d[3 * NTHR] = v##3; _d[4 * NTHR] = v##4; _d[5 * NTHR] = v##5;      \
         _d[6 * NTHR] = v##6; _d[7 * NTHR] = v##7; } while (0)

// 2-deep software-pipelined copy, 8-wide bursts (32 KB batches).
// Static register names only; compiler emits counted vmcnt (never drains).
__device__ __forceinline__ void copy_pipe(const f32x4* __restrict__ src,
                                          f32x4* __restrict__ dst,
                                          int b0, int b1, int cid, int nblk, int t) {
    int btA = b0 + cid;
    if (btA >= b1) return;
    f32x4 va0, va1, va2, va3, va4, va5, va6, va7;
    f32x4 vb0, vb1, vb2, vb3, vb4, vb5, vb6, vb7;
    LOAD8(va, src + (size_t)btA * BATCH4 + t);
    int btB = btA + nblk;
    while (btB < b1) {
        LOAD8(vb, src + (size_t)btB * BATCH4 + t);
        STORE8(va, dst + (size_t)btA * BATCH4 + t);
        btA = btB; btB += nblk;
        if (btB >= b1) {
            STORE8(vb, dst + (size_t)btA * BATCH4 + t);
            return;
        }
        LOAD8(va, src + (size_t)btB * BATCH4 + t);
        STORE8(vb, dst + (size_t)btA * BATCH4 + t);
        btA = btB; btB += nblk;
    }
    STORE8(va, dst + (size_t)btA * BATCH4 + t);
}

// ---------------- K1: prep only (100 blocks, ~5 us) -------------------------
__global__ __launch_bounds__(NTHR)
void k1_prep(const float* __restrict__ A, const float* __restrict__ K,
             float* __restrict__ W1, float* __restrict__ W2,
             float* __restrict__ knorm) {
    const int blk = blockIdx.x, t = threadIdx.x;
    __shared__ float red[NTHR];
    const int k = blk;
    const float* Ar = A + (size_t)k * CDIM;
    const float* Kr = K + (size_t)k * CDIM;

    float m = -INFINITY;
    for (int d = t; d < CDIM; d += NTHR) m = fmaxf(m, Ar[d]);
    red[t] = m; __syncthreads();
    for (int s = 128; s > 0; s >>= 1) { if (t < s) red[t] = fmaxf(red[t], red[t + s]); __syncthreads(); }
    m = red[0]; __syncthreads();

    float sum = 0.f;
    for (int d = t; d < CDIM; d += NTHR) sum += expf(Ar[d] - m);
    red[t] = sum; __syncthreads();
    for (int s = 128; s > 0; s >>= 1) { if (t < s) red[t] += red[t + s]; __syncthreads(); }
    sum = red[0]; __syncthreads();
    const float inv = 1.0f / sum;

    float ksq = 0.f;
    for (int d = t; d < CDIM; d += NTHR) { float kv = Kr[d]; ksq += kv * kv; }
    red[t] = ksq; __syncthreads();
    for (int s = 128; s > 0; s >>= 1) { if (t < s) red[t] += red[t + s]; __syncthreads(); }
    if (t == 0) knorm[k] = fmaxf(sqrtf(red[0]), COSEPS);

    for (int d = t; d < CDIM; d += NTHR) {
        float a_sm = expf(Ar[d] - m) * inv;
        W1[(size_t)k * CDIM + d] = a_sm * Kr[d];
        W2[(size_t)k * CDIM + d] = a_sm * a_sm;
    }
}

// ---------------- K2: aq (1024 blocks) + copy batches [0,nbH) ---------------
__global__ __launch_bounds__(NTHR)
void k2_aq_copy(const float* __restrict__ xq,
                const float* __restrict__ W1, const float* __restrict__ W2,
                const float* __restrict__ knorm, float* __restrict__ aq,
                const f32x4* __restrict__ src4, f32x4* __restrict__ dst4,
                int nbH) {
    const int blk = blockIdx.x, t = threadIdx.x;
    const int role = (blk >> 3) & 1;                // both roles on every XCD
    const int id   = ((blk >> 4) << 3) | (blk & 7); // 0..1023 per role

    if (role) {
        copy_pipe(src4, dst4, 0, nbH, id, 1024, t);
        return;
    }

    __shared__ f32x4 xs4[CDIM / 4];
    const int b = id;
    const f32x4* xq4 = (const f32x4*)(xq + (size_t)b * CDIM);
    for (int i = t; i < CDIM / 4; i += NTHR) xs4[i] = xq4[i];
    __syncthreads();

    const int wave = t >> 6, lane = t & 63;
    for (int k = wave; k < POOL; k += 4) {
        const f32x4* w14 = (const f32x4*)(W1 + (size_t)k * CDIM);
        const f32x4* w24 = (const f32x4*)(W2 + (size_t)k * CDIM);
        float s1 = 0.f, s2 = 0.f;
        #pragma unroll
        for (int i = 0; i < CDIM / 4 / 64; ++i) {   // 3 iters
            const int d4 = lane + i * 64;
            f32x4 x  = xs4[d4];
            f32x4 w1 = w14[d4];
            f32x4 w2 = w24[d4];
            s1 += x.x * w1.x + x.y * w1.y + x.z * w1.z + x.w * w1.w;
            s2 += x.x * x.x * w2.x + x.y * x.y * w2.y
                + x.z * x.z * w2.z + x.w * x.w * w2.w;
        }
        for (int off = 32; off > 0; off >>= 1) {
            s1 += __shfl_down(s1, off);
            s2 += __shfl_down(s2, off);
        }
        if (lane == 0) {
            float an = fmaxf(sqrtf(s2), COSEPS);
            float v  = s1 / (an * knorm[k]);
            aq[(size_t)b * POOL + k] = (v + 1.0f) * 0.5f;
        }
    }
}

// ---------------- K3: p-contraction (1024 blocks) + copy [nbH,NB) + tail ----
__global__ __launch_bounds__(NTHR)
void k3_p_copy(const float* __restrict__ aq, const float* __restrict__ p,
               float* __restrict__ out,
               const f32x4* __restrict__ src4, f32x4* __restrict__ dst4,
               int nbH, int NB, int n4) {
    const int blk = blockIdx.x, t = threadIdx.x;
    const int role = (blk >> 3) & 1;
    const int id   = ((blk >> 4) << 3) | (blk & 7);

    if (role) {
        copy_pipe(src4, dst4, nbH, NB, id, 1024, t);
        // tail: n4 % BATCH4 float4s (0 for actual shapes, guarded anyway)
        for (int i = NB * BATCH4 + id * NTHR + t; i < n4; i += 1024 * NTHR)
            dst4[i] = src4[i];
        return;
    }

    __shared__ float a_s[POOL * 8];
    const int l  = id & 7;
    const int bg = id >> 3;

    for (int i = t; i < POOL * 8; i += NTHR) {
        int bb = i & 7, k = i >> 3;
        a_s[i] = aq[(size_t)(bg * 8 + bb) * POOL + k];
    }
    __syncthreads();

    const float* pl = p + (size_t)l * POOL * CDIM + t;
    float acc[8][3];
    #pragma unroll
    for (int bb = 0; bb < 8; ++bb)
        #pragma unroll
        for (int j = 0; j < 3; ++j) acc[bb][j] = 0.f;

    for (int k = 0; k < POOL; ++k) {
        float p0 = pl[(size_t)k * CDIM];
        float p1 = pl[(size_t)k * CDIM + 256];
        float p2 = pl[(size_t)k * CDIM + 512];
        #pragma unroll
        for (int bb = 0; bb < 8; ++bb) {
            float a = a_s[k * 8 + bb];
            acc[bb][0] += a * p0;
            acc[bb][1] += a * p1;
            acc[bb][2] += a * p2;
        }
    }

    const size_t EK_SZ = (size_t)B_SZ * 4 * CDIM;
    #pragma unroll
    for (int bb = 0; bb < 8; ++bb) {
        int b = bg * 8 + bb;
        float* dst = (l < 4)
            ? out + (size_t)b * (4 * CDIM) + (size_t)l * CDIM
            : out + EK_SZ + (size_t)b * (4 * CDIM) + (size_t)(l - 4) * CDIM;
        dst[t]       = acc[bb][0];
        dst[t + 256] = acc[bb][1];
        dst[t + 512] = acc[bb][2];
    }
}

extern "C" void kernel_launch(void* const* d_in, const int* in_sizes, int n_in,
                              void* d_out, int out_size, void* d_ws, size_t ws_size,
                              hipStream_t stream) {
    const float* x_querry = (const float*)d_in[0];
    const float* x_block  = (const float*)d_in[1];
    const float* K        = (const float*)d_in[2];
    const float* A        = (const float*)d_in[3];
    const float* p        = (const float*)d_in[4];
    float* out = (float*)d_out;

    // workspace layout (floats)
    float* W1    = (float*)d_ws;                 // 100*768
    float* W2    = W1 + POOL * CDIM;             // 100*768
    float* knorm = W2 + POOL * CDIM;             // 100 (pad 128)
    float* aq    = knorm + 128;                  // 1024*100

    const size_t EK_SZ = (size_t)B_SZ * 4 * CDIM;
    const f32x4* src4 = (const f32x4*)x_block;
    f32x4* dst4 = (f32x4*)(out + 2 * EK_SZ);

    const int n4 = in_sizes[1] / 4;              // 38,731,776
    const int NB = n4 / BATCH4;                  // 18,912 full 32KB batches
    const int nbH = NB / 2;                      // 50% / 50% between K2 and K3

    k1_prep   <<<POOL, NTHR, 0, stream>>>(A, K, W1, W2, knorm);
    k2_aq_copy<<<2048, NTHR, 0, stream>>>(x_querry, W1, W2, knorm, aq,
                                          src4, dst4, nbH);
    k3_p_copy <<<2048, NTHR, 0, stream>>>(aq, p, out, src4, dst4,
                                          nbH, NB, n4);
}

// Round 16
// 246.421 us; speedup vs baseline: 1.0960x; 1.0960x over previous
//
#include <hip/hip_runtime.h>
#include <math.h>

#define B_SZ   1024
#define CDIM   768
#define POOL   100
#define COSEPS 1e-6f
#define NTHR   256
#define BATCH4 2048   // float4s per batch = 8 * NTHR (32 KB)

typedef __attribute__((ext_vector_type(4))) float f32x4;

#define LOAD8(v, base)                                                       \
    do { const f32x4* _s = (base);                                           \
         v##0 = _s[0];        v##1 = _s[NTHR];     v##2 = _s[2 * NTHR];      \
         v##3 = _s[3 * NTHR]; v##4 = _s[4 * NTHR]; v##5 = _s[5 * NTHR];      \
         v##6 = _s[6 * NTHR]; v##7 = _s[7 * NTHR]; } while (0)
#define STORE8NT(v, base)                                                    \
    do { f32x4* _d = (base);                                                 \
         __builtin_nontemporal_store(v##0, _d);                              \
         __builtin_nontemporal_store(v##1, _d + NTHR);                       \
         __builtin_nontemporal_store(v##2, _d + 2 * NTHR);                   \
         __builtin_nontemporal_store(v##3, _d + 3 * NTHR);                   \
         __builtin_nontemporal_store(v##4, _d + 4 * NTHR);                   \
         __builtin_nontemporal_store(v##5, _d + 5 * NTHR);                   \
         __builtin_nontemporal_store(v##6, _d + 6 * NTHR);                   \
         __builtin_nontemporal_store(v##7, _d + 7 * NTHR); } while (0)

// 2-deep software-pipelined copy, 8-wide bursts (32 KB batches).
// Plain loads + NON-TEMPORAL stores (final clean probe of write-allocate cost).
__device__ __forceinline__ void copy_pipe(const f32x4* __restrict__ src,
                                          f32x4* __restrict__ dst,
                                          int b0, int b1, int cid, int nblk, int t) {
    int btA = b0 + cid;
    if (btA >= b1) return;
    f32x4 va0, va1, va2, va3, va4, va5, va6, va7;
    f32x4 vb0, vb1, vb2, vb3, vb4, vb5, vb6, vb7;
    LOAD8(va, src + (size_t)btA * BATCH4 + t);
    int btB = btA + nblk;
    while (btB < b1) {
        LOAD8(vb, src + (size_t)btB * BATCH4 + t);
        STORE8NT(va, dst + (size_t)btA * BATCH4 + t);
        btA = btB; btB += nblk;
        if (btB >= b1) {
            STORE8NT(vb, dst + (size_t)btA * BATCH4 + t);
            return;
        }
        LOAD8(va, src + (size_t)btB * BATCH4 + t);
        STORE8NT(vb, dst + (size_t)btA * BATCH4 + t);
        btA = btB; btB += nblk;
    }
    STORE8NT(va, dst + (size_t)btA * BATCH4 + t);
}

// ---------------- K1 (1024 blocks): prep (0..99, then join) + copy [0,nb1) --
__global__ __launch_bounds__(NTHR)
void k1_prep_copy(const float* __restrict__ A, const float* __restrict__ K,
                  float* __restrict__ W1, float* __restrict__ W2,
                  float* __restrict__ knorm,
                  const f32x4* __restrict__ src4, f32x4* __restrict__ dst4,
                  int nb1) {
    const int blk = blockIdx.x, t = threadIdx.x;
    if (blk < POOL) {
        __shared__ float red[NTHR];
        const int k = blk;
        const float* Ar = A + (size_t)k * CDIM;
        const float* Kr = K + (size_t)k * CDIM;

        float m = -INFINITY;
        for (int d = t; d < CDIM; d += NTHR) m = fmaxf(m, Ar[d]);
        red[t] = m; __syncthreads();
        for (int s = 128; s > 0; s >>= 1) { if (t < s) red[t] = fmaxf(red[t], red[t + s]); __syncthreads(); }
        m = red[0]; __syncthreads();

        float sum = 0.f;
        for (int d = t; d < CDIM; d += NTHR) sum += expf(Ar[d] - m);
        red[t] = sum; __syncthreads();
        for (int s = 128; s > 0; s >>= 1) { if (t < s) red[t] += red[t + s]; __syncthreads(); }
        sum = red[0]; __syncthreads();
        const float inv = 1.0f / sum;

        float ksq = 0.f;
        for (int d = t; d < CDIM; d += NTHR) { float kv = Kr[d]; ksq += kv * kv; }
        red[t] = ksq; __syncthreads();
        for (int s = 128; s > 0; s >>= 1) { if (t < s) red[t] += red[t + s]; __syncthreads(); }
        if (t == 0) knorm[k] = fmaxf(sqrtf(red[0]), COSEPS);

        for (int d = t; d < CDIM; d += NTHR) {
            float a_sm = expf(Ar[d] - m) * inv;
            W1[(size_t)k * CDIM + d] = a_sm * Kr[d];
            W2[(size_t)k * CDIM + d] = a_sm * a_sm;
        }
        __syncthreads();
    }
    // all 1024 blocks stride the same range; prep blocks join ~5us late
    copy_pipe(src4, dst4, 0, nb1, blk, (int)gridDim.x, t);
}

// ---------------- K2: aq (1024 blocks) + copy batches [nb1,nb2) -------------
__global__ __launch_bounds__(NTHR)
void k2_aq_copy(const float* __restrict__ xq,
                const float* __restrict__ W1, const float* __restrict__ W2,
                const float* __restrict__ knorm, float* __restrict__ aq,
                const f32x4* __restrict__ src4, f32x4* __restrict__ dst4,
                int nb1, int nb2) {
    const int blk = blockIdx.x, t = threadIdx.x;
    const int role = (blk >> 3) & 1;                // both roles on every XCD
    const int id   = ((blk >> 4) << 3) | (blk & 7); // 0..1023 per role

    if (role) {
        copy_pipe(src4, dst4, nb1, nb2, id, 1024, t);
        return;
    }

    __shared__ f32x4 xs4[CDIM / 4];
    const int b = id;
    const f32x4* xq4 = (const f32x4*)(xq + (size_t)b * CDIM);
    for (int i = t; i < CDIM / 4; i += NTHR) xs4[i] = xq4[i];
    __syncthreads();

    const int wave = t >> 6, lane = t & 63;
    for (int k = wave; k < POOL; k += 4) {
        const f32x4* w14 = (const f32x4*)(W1 + (size_t)k * CDIM);
        const f32x4* w24 = (const f32x4*)(W2 + (size_t)k * CDIM);
        float s1 = 0.f, s2 = 0.f;
        #pragma unroll
        for (int i = 0; i < CDIM / 4 / 64; ++i) {   // 3 iters
            const int d4 = lane + i * 64;
            f32x4 x  = xs4[d4];
            f32x4 w1 = w14[d4];
            f32x4 w2 = w24[d4];
            s1 += x.x * w1.x + x.y * w1.y + x.z * w1.z + x.w * w1.w;
            s2 += x.x * x.x * w2.x + x.y * x.y * w2.y
                + x.z * x.z * w2.z + x.w * x.w * w2.w;
        }
        for (int off = 32; off > 0; off >>= 1) {
            s1 += __shfl_down(s1, off);
            s2 += __shfl_down(s2, off);
        }
        if (lane == 0) {
            float an = fmaxf(sqrtf(s2), COSEPS);
            float v  = s1 / (an * knorm[k]);
            aq[(size_t)b * POOL + k] = (v + 1.0f) * 0.5f;
        }
    }
}

// ---------------- K3: p-contraction (1024 blocks) + copy [nb2,NB) + tail ----
__global__ __launch_bounds__(NTHR)
void k3_p_copy(const float* __restrict__ aq, const float* __restrict__ p,
               float* __restrict__ out,
               const f32x4* __restrict__ src4, f32x4* __restrict__ dst4,
               int nb2, int NB, int n4) {
    const int blk = blockIdx.x, t = threadIdx.x;
    const int role = (blk >> 3) & 1;
    const int id   = ((blk >> 4) << 3) | (blk & 7);

    if (role) {
        copy_pipe(src4, dst4, nb2, NB, id, 1024, t);
        // tail: n4 % BATCH4 float4s (0 for actual shapes, guarded anyway)
        for (int i = NB * BATCH4 + id * NTHR + t; i < n4; i += 1024 * NTHR)
            dst4[i] = src4[i];
        return;
    }

    __shared__ float a_s[POOL * 8];
    const int l  = id & 7;
    const int bg = id >> 3;

    for (int i = t; i < POOL * 8; i += NTHR) {
        int bb = i & 7, k = i >> 3;
        a_s[i] = aq[(size_t)(bg * 8 + bb) * POOL + k];
    }
    __syncthreads();

    const float* pl = p + (size_t)l * POOL * CDIM + t;
    float acc[8][3];
    #pragma unroll
    for (int bb = 0; bb < 8; ++bb)
        #pragma unroll
        for (int j = 0; j < 3; ++j) acc[bb][j] = 0.f;

    for (int k = 0; k < POOL; ++k) {
        float p0 = pl[(size_t)k * CDIM];
        float p1 = pl[(size_t)k * CDIM + 256];
        float p2 = pl[(size_t)k * CDIM + 512];
        #pragma unroll
        for (int bb = 0; bb < 8; ++bb) {
            float a = a_s[k * 8 + bb];
            acc[bb][0] += a * p0;
            acc[bb][1] += a * p1;
            acc[bb][2] += a * p2;
        }
    }

    const size_t EK_SZ = (size_t)B_SZ * 4 * CDIM;
    #pragma unroll
    for (int bb = 0; bb < 8; ++bb) {
        int b = bg * 8 + bb;
        float* dst = (l < 4)
            ? out + (size_t)b * (4 * CDIM) + (size_t)l * CDIM
            : out + EK_SZ + (size_t)b * (4 * CDIM) + (size_t)(l - 4) * CDIM;
        dst[t]       = acc[bb][0];
        dst[t + 256] = acc[bb][1];
        dst[t + 512] = acc[bb][2];
    }
}

extern "C" void kernel_launch(void* const* d_in, const int* in_sizes, int n_in,
                              void* d_out, int out_size, void* d_ws, size_t ws_size,
                              hipStream_t stream) {
    const float* x_querry = (const float*)d_in[0];
    const float* x_block  = (const float*)d_in[1];
    const float* K        = (const float*)d_in[2];
    const float* A        = (const float*)d_in[3];
    const float* p        = (const float*)d_in[4];
    float* out = (float*)d_out;

    // workspace layout (floats)
    float* W1    = (float*)d_ws;                 // 100*768
    float* W2    = W1 + POOL * CDIM;             // 100*768
    float* knorm = W2 + POOL * CDIM;             // 100 (pad 128)
    float* aq    = knorm + 128;                  // 1024*100

    const size_t EK_SZ = (size_t)B_SZ * 4 * CDIM;
    const f32x4* src4 = (const f32x4*)x_block;
    f32x4* dst4 = (f32x4*)(out + 2 * EK_SZ);

    const int n4 = in_sizes[1] / 4;              // 38,731,776
    const int NB = n4 / BATCH4;                  // 18,912 full 32KB batches

    // shares: 50% / 25% / 25% (R13/R14 best)
    const int u16 = NB / 16;
    const int nb1 = u16 * 8;
    const int nb2 = u16 * 12;

    k1_prep_copy<<<1024, NTHR, 0, stream>>>(A, K, W1, W2, knorm, src4, dst4, nb1);
    k2_aq_copy  <<<2048, NTHR, 0, stream>>>(x_querry, W1, W2, knorm, aq,
                                            src4, dst4, nb1, nb2);
    k3_p_copy   <<<2048, NTHR, 0, stream>>>(aq, p, out, src4, dst4,
                                            nb2, NB, n4);
}

// Round 17
// 235.620 us; speedup vs baseline: 1.1463x; 1.0458x over previous
//
#include <hip/hip_runtime.h>
#include <math.h>

#define B_SZ   1024
#define CDIM   768
#define POOL   100
#define COSEPS 1e-6f
#define NTHR   256
#define BATCH4 2048   // float4s per batch = 8 * NTHR (32 KB)

typedef __attribute__((ext_vector_type(4))) float f32x4;

#define LOAD8NT(v, base)                                                     \
    do { const f32x4* _s = (base);                                           \
         v##0 = __builtin_nontemporal_load(_s);                              \
         v##1 = __builtin_nontemporal_load(_s + NTHR);                       \
         v##2 = __builtin_nontemporal_load(_s + 2 * NTHR);                   \
         v##3 = __builtin_nontemporal_load(_s + 3 * NTHR);                   \
         v##4 = __builtin_nontemporal_load(_s + 4 * NTHR);                   \
         v##5 = __builtin_nontemporal_load(_s + 5 * NTHR);                   \
         v##6 = __builtin_nontemporal_load(_s + 6 * NTHR);                   \
         v##7 = __builtin_nontemporal_load(_s + 7 * NTHR); } while (0)
#define STORE8NT(v, base)                                                    \
    do { f32x4* _d = (base);                                                 \
         __builtin_nontemporal_store(v##0, _d);                              \
         __builtin_nontemporal_store(v##1, _d + NTHR);                       \
         __builtin_nontemporal_store(v##2, _d + 2 * NTHR);                   \
         __builtin_nontemporal_store(v##3, _d + 3 * NTHR);                   \
         __builtin_nontemporal_store(v##4, _d + 4 * NTHR);                   \
         __builtin_nontemporal_store(v##5, _d + 5 * NTHR);                   \
         __builtin_nontemporal_store(v##6, _d + 6 * NTHR);                   \
         __builtin_nontemporal_store(v##7, _d + 7 * NTHR); } while (0)

// 2-deep software-pipelined copy, 8-wide bursts (32 KB batches).
// NT loads + NT stores: neither stream allocates in L2.
__device__ __forceinline__ void copy_pipe(const f32x4* __restrict__ src,
                                          f32x4* __restrict__ dst,
                                          int b0, int b1, int cid, int nblk, int t) {
    int btA = b0 + cid;
    if (btA >= b1) return;
    f32x4 va0, va1, va2, va3, va4, va5, va6, va7;
    f32x4 vb0, vb1, vb2, vb3, vb4, vb5, vb6, vb7;
    LOAD8NT(va, src + (size_t)btA * BATCH4 + t);
    int btB = btA + nblk;
    while (btB < b1) {
        LOAD8NT(vb, src + (size_t)btB * BATCH4 + t);
        STORE8NT(va, dst + (size_t)btA * BATCH4 + t);
        btA = btB; btB += nblk;
        if (btB >= b1) {
            STORE8NT(vb, dst + (size_t)btA * BATCH4 + t);
            return;
        }
        LOAD8NT(va, src + (size_t)btB * BATCH4 + t);
        STORE8NT(vb, dst + (size_t)btA * BATCH4 + t);
        btA = btB; btB += nblk;
    }
    STORE8NT(va, dst + (size_t)btA * BATCH4 + t);
}

// ---------------- K1 (1024 blocks): prep (0..99, then join) + copy [0,nb1) --
__global__ __launch_bounds__(NTHR)
void k1_prep_copy(const float* __restrict__ A, const float* __restrict__ K,
                  float* __restrict__ W1, float* __restrict__ W2,
                  float* __restrict__ knorm,
                  const f32x4* __restrict__ src4, f32x4* __restrict__ dst4,
                  int nb1) {
    const int blk = blockIdx.x, t = threadIdx.x;
    if (blk < POOL) {
        __shared__ float red[NTHR];
        const int k = blk;
        const float* Ar = A + (size_t)k * CDIM;
        const float* Kr = K + (size_t)k * CDIM;

        float m = -INFINITY;
        for (int d = t; d < CDIM; d += NTHR) m = fmaxf(m, Ar[d]);
        red[t] = m; __syncthreads();
        for (int s = 128; s > 0; s >>= 1) { if (t < s) red[t] = fmaxf(red[t], red[t + s]); __syncthreads(); }
        m = red[0]; __syncthreads();

        float sum = 0.f;
        for (int d = t; d < CDIM; d += NTHR) sum += expf(Ar[d] - m);
        red[t] = sum; __syncthreads();
        for (int s = 128; s > 0; s >>= 1) { if (t < s) red[t] += red[t + s]; __syncthreads(); }
        sum = red[0]; __syncthreads();
        const float inv = 1.0f / sum;

        float ksq = 0.f;
        for (int d = t; d < CDIM; d += NTHR) { float kv = Kr[d]; ksq += kv * kv; }
        red[t] = ksq; __syncthreads();
        for (int s = 128; s > 0; s >>= 1) { if (t < s) red[t] += red[t + s]; __syncthreads(); }
        if (t == 0) knorm[k] = fmaxf(sqrtf(red[0]), COSEPS);

        for (int d = t; d < CDIM; d += NTHR) {
            float a_sm = expf(Ar[d] - m) * inv;
            W1[(size_t)k * CDIM + d] = a_sm * Kr[d];
            W2[(size_t)k * CDIM + d] = a_sm * a_sm;
        }
        __syncthreads();
    }
    // all 1024 blocks stride the same range; prep blocks join ~5us late
    copy_pipe(src4, dst4, 0, nb1, blk, (int)gridDim.x, t);
}

// ---------------- K2: aq (1024 blocks) + copy batches [nb1,nb2) -------------
__global__ __launch_bounds__(NTHR)
void k2_aq_copy(const float* __restrict__ xq,
                const float* __restrict__ W1, const float* __restrict__ W2,
                const float* __restrict__ knorm, float* __restrict__ aq,
                const f32x4* __restrict__ src4, f32x4* __restrict__ dst4,
                int nb1, int nb2) {
    const int blk = blockIdx.x, t = threadIdx.x;
    const int role = (blk >> 3) & 1;                // both roles on every XCD
    const int id   = ((blk >> 4) << 3) | (blk & 7); // 0..1023 per role

    if (role) {
        copy_pipe(src4, dst4, nb1, nb2, id, 1024, t);
        return;
    }

    __shared__ f32x4 xs4[CDIM / 4];
    const int b = id;
    const f32x4* xq4 = (const f32x4*)(xq + (size_t)b * CDIM);
    for (int i = t; i < CDIM / 4; i += NTHR) xs4[i] = xq4[i];
    __syncthreads();

    const int wave = t >> 6, lane = t & 63;
    for (int k = wave; k < POOL; k += 4) {
        const f32x4* w14 = (const f32x4*)(W1 + (size_t)k * CDIM);
        const f32x4* w24 = (const f32x4*)(W2 + (size_t)k * CDIM);
        float s1 = 0.f, s2 = 0.f;
        #pragma unroll
        for (int i = 0; i < CDIM / 4 / 64; ++i) {   // 3 iters
            const int d4 = lane + i * 64;
            f32x4 x  = xs4[d4];
            f32x4 w1 = w14[d4];
            f32x4 w2 = w24[d4];
            s1 += x.x * w1.x + x.y * w1.y + x.z * w1.z + x.w * w1.w;
            s2 += x.x * x.x * w2.x + x.y * x.y * w2.y
                + x.z * x.z * w2.z + x.w * x.w * w2.w;
        }
        for (int off = 32; off > 0; off >>= 1) {
            s1 += __shfl_down(s1, off);
            s2 += __shfl_down(s2, off);
        }
        if (lane == 0) {
            float an = fmaxf(sqrtf(s2), COSEPS);
            float v  = s1 / (an * knorm[k]);
            aq[(size_t)b * POOL + k] = (v + 1.0f) * 0.5f;
        }
    }
}

// ---------------- K3: p-contraction (1024 blocks) + copy [nb2,NB) + tail ----
__global__ __launch_bounds__(NTHR)
void k3_p_copy(const float* __restrict__ aq, const float* __restrict__ p,
               float* __restrict__ out,
               const f32x4* __restrict__ src4, f32x4* __restrict__ dst4,
               int nb2, int NB, int n4) {
    const int blk = blockIdx.x, t = threadIdx.x;
    const int role = (blk >> 3) & 1;
    const int id   = ((blk >> 4) << 3) | (blk & 7);

    if (role) {
        copy_pipe(src4, dst4, nb2, NB, id, 1024, t);
        // tail: n4 % BATCH4 float4s (0 for actual shapes, guarded anyway)
        for (int i = NB * BATCH4 + id * NTHR + t; i < n4; i += 1024 * NTHR)
            dst4[i] = src4[i];
        return;
    }

    __shared__ float a_s[POOL * 8];
    const int l  = id & 7;
    const int bg = id >> 3;

    for (int i = t; i < POOL * 8; i += NTHR) {
        int bb = i & 7, k = i >> 3;
        a_s[i] = aq[(size_t)(bg * 8 + bb) * POOL + k];
    }
    __syncthreads();

    const float* pl = p + (size_t)l * POOL * CDIM + t;
    float acc[8][3];
    #pragma unroll
    for (int bb = 0; bb < 8; ++bb)
        #pragma unroll
        for (int j = 0; j < 3; ++j) acc[bb][j] = 0.f;

    for (int k = 0; k < POOL; ++k) {
        float p0 = pl[(size_t)k * CDIM];
        float p1 = pl[(size_t)k * CDIM + 256];
        float p2 = pl[(size_t)k * CDIM + 512];
        #pragma unroll
        for (int bb = 0; bb < 8; ++bb) {
            float a = a_s[k * 8 + bb];
            acc[bb][0] += a * p0;
            acc[bb][1] += a * p1;
            acc[bb][2] += a * p2;
        }
    }

    const size_t EK_SZ = (size_t)B_SZ * 4 * CDIM;
    #pragma unroll
    for (int bb = 0; bb < 8; ++bb) {
        int b = bg * 8 + bb;
        float* dst = (l < 4)
            ? out + (size_t)b * (4 * CDIM) + (size_t)l * CDIM
            : out + EK_SZ + (size_t)b * (4 * CDIM) + (size_t)(l - 4) * CDIM;
        dst[t]       = acc[bb][0];
        dst[t + 256] = acc[bb][1];
        dst[t + 512] = acc[bb][2];
    }
}

extern "C" void kernel_launch(void* const* d_in, const int* in_sizes, int n_in,
                              void* d_out, int out_size, void* d_ws, size_t ws_size,
                              hipStream_t stream) {
    const float* x_querry = (const float*)d_in[0];
    const float* x_block  = (const float*)d_in[1];
    const float* K        = (const float*)d_in[2];
    const float* A        = (const float*)d_in[3];
    const float* p        = (const float*)d_in[4];
    float* out = (float*)d_out;

    // workspace layout (floats)
    float* W1    = (float*)d_ws;                 // 100*768
    float* W2    = W1 + POOL * CDIM;             // 100*768
    float* knorm = W2 + POOL * CDIM;             // 100 (pad 128)
    float* aq    = knorm + 128;                  // 1024*100

    const size_t EK_SZ = (size_t)B_SZ * 4 * CDIM;
    const f32x4* src4 = (const f32x4*)x_block;
    f32x4* dst4 = (f32x4*)(out + 2 * EK_SZ);

    const int n4 = in_sizes[1] / 4;              // 38,731,776
    const int NB = n4 / BATCH4;                  // 18,912 full 32KB batches

    // shares: 50% / 25% / 25% (R13/R14 best)
    const int u16 = NB / 16;
    const int nb1 = u16 * 8;
    const int nb2 = u16 * 12;

    k1_prep_copy<<<1024, NTHR, 0, stream>>>(A, K, W1, W2, knorm, src4, dst4, nb1);
    k2_aq_copy  <<<2048, NTHR, 0, stream>>>(x_querry, W1, W2, knorm, aq,
                                            src4, dst4, nb1, nb2);
    k3_p_copy   <<<2048, NTHR, 0, stream>>>(aq, p, out, src4, dst4,
                                            nb2, NB, n4);
}